// Round 12
// baseline (173.223 us; speedup 1.0000x reference)
//
#include <hip/hip_runtime.h>

// out[o] = sum_t d1[t + o - 301] * d2[t],  o in [0,603), t in [0,3000)
// Parity-split GEMM per channel:
//   o = 2*(16a + m) + par,  C_par[m,a] = sum_s d1[s + 2m + par - 301] * d2[s - 32a]
//
// R12 = R11 with the compile fix (no __floats2bfloat162_rn in ROCm 7.2;
// use the same RNE bit-pack as the A side). B OPERAND FROM GLOBAL (no l2
// LDS): R9 counters showed the LDS pipe is the binding resource (~100% util
// at saturation); B's fragment is 8 contiguous 32B-aligned f32 of d2 -> load
// direct from global (L1/L2-resident, 12KB/ch), pack to bf16 in-reg,
// 2-step-ahead pipeline. B windows are fully in or fully out of [0,3000)
// (eb = 256+8q-32r+32i is 0 mod 8), so one clamp+select per step replaces
// all pad logic. FIFO keeps tile1 = tile0@i-16. A side (LDS, streamed
// staging, guards) byte-identical to R8/R4 (verified). LDS 15.4KB -> 6.8KB.

#define NT    3000
#define NOUT  603
#define BLOCK 64
#define L1DW  1696

typedef short bf16x8 __attribute__((ext_vector_type(8)));
typedef float f32x4  __attribute__((ext_vector_type(4)));

static __device__ __forceinline__ uint f2bf(float f) {
    union { float f; uint u; } a; a.f = f;            // RNE f32 -> bf16
    return (a.u + 0x7fffu + ((a.u >> 16) & 1u)) >> 16;
}

static __device__ __forceinline__ int pk2(float lo, float hi) {
    return (int)(f2bf(lo) | (f2bf(hi) << 16));
}

static __device__ __forceinline__ int4 packB(float4 x, float4 y) {
    int4 p;
    p.x = pk2(x.x, x.y); p.y = pk2(x.z, x.w);
    p.z = pk2(y.x, y.y); p.w = pk2(y.z, y.w);
    return p;
}

__global__ __launch_bounds__(BLOCK, 4) void xcorr_mfma(
    const float* __restrict__ d1g, const float* __restrict__ d2g,
    float* __restrict__ out)
{
    __shared__ __align__(16) uint l1[L1DW];

    const int lane = threadIdx.x & 63;
    const int q = lane >> 4, r = lane & 15;
    const int ch = blockIdx.x;
    const float* __restrict__ g1 = d1g + (size_t)ch * NT;
    const float* __restrict__ g2 = d2g + (size_t)ch * NT;

    // --- Zero A pad regions (same-wave LDS ordering is program order).
    for (int j = lane; j < 196; j += BLOCK) {
        const int dw = (j < 152) ? j : 1652 + (j - 152);
        l1[dw] = 0u;
    }

    // --- A staging: lane handles dwords [dstart+4*lane, +4).
    auto stageA = [&](int dstart) {
        const int d = dstart + 4 * lane;
        const int e0 = 2 * (d - 152);
        if (e0 < NT) {
            const float4 v = *(const float4*)(g1 + e0);
            const float4 w = *(const float4*)(g1 + e0 + 4);
            int4 p;
            p.x = pk2(v.x, v.y);
            p.y = pk2(v.z, v.w);
            p.z = pk2(w.x, w.y);
            p.w = pk2(w.z, w.w);
            *(int4*)(l1 + d) = p;
        }
    };

    // --- Prologue: A dwords [152,664).
    stageA(152); stageA(408);

    // --- B pipeline bases. Step S: eb(S) = ebBase + 32*S, frag = d2[eb..eb+8).
    const int ebBase = 256 + 8 * q - 32 * r;
    auto loadB = [&](int eb, float4& x, float4& y) -> bool {
        const bool ok = (eb >= 0) && (eb <= 2992);
        const int ec = eb < 0 ? 0 : (eb > 2992 ? 2992 : eb);
        x = *(const float4*)(g2 + ec);
        y = *(const float4*)(g2 + ec + 4);
        return ok;
    };

    // --- B FIFO prefill from global: slot s <- tile0 frag of step s-16.
    int4 fifo[16];
    #pragma unroll
    for (int s = 0; s < 16; ++s) {
        float4 x, y;
        const bool ok = loadB(ebBase - 512 + 32 * s, x, y);
        const int4 pv = packB(x, y);
        fifo[s] = ok ? pv : int4{0, 0, 0, 0};
    }

    // --- B 2-ahead register pipeline prologue.
    int4 pkE, pkO;                    // packed frags: even-step, odd-step
    float4 fAx, fAy, fBx, fBy;        // in-flight f32 pairs
    bool okA_, okB_;
    {
        float4 x, y;
        const bool ok0 = loadB(ebBase, x, y);            // frag(0)
        const int4 pv = packB(x, y);
        pkE = ok0 ? pv : int4{0, 0, 0, 0};
        okB_ = loadB(ebBase + 32, fBx, fBy);             // f32(1)
    }
    int ebN = ebBase + 64;            // address of step S+2 issued at step S

    f32x4 a00 = {0.f,0.f,0.f,0.f};   // aPT: P = parity, T = n-tile
    f32x4 a10 = {0.f,0.f,0.f,0.f};
    f32x4 a01 = {0.f,0.f,0.f,0.f};
    f32x4 a11 = {0.f,0.f,0.f,0.f};

    int da = 130 + 4 * q + r;        // A dword base (+16/step)
    int aPre = 664;                  // A staged frontier

    for (int c = 0; c < 6; ++c) {
        // A-stream prefetch loads (future chunks; guards skip past-data units).
        const int dA = aPre + 4 * lane, eA = 2 * (dA - 152);
        const bool okSt = eA < NT;
        float4 va0, va1;
        if (okSt) { va0 = *(const float4*)(g1 + eA); va1 = *(const float4*)(g1 + eA + 4); }

        #pragma unroll
        for (int u = 0; u < 16; ++u) {
            const bool evenU = ((u & 1) == 0);

            // Issue global loads for step S+2 (consumed 2 steps later).
            {
                float4 x, y;
                const bool ok = loadB(ebN, x, y);
                if (evenU) { fAx = x; fAy = y; okA_ = ok; }
                else       { fBx = x; fBy = y; okB_ = ok; }
                ebN += 32;
            }

            // A fragment from LDS (5 dwords, misaligned window).
            const uint* pa = (const uint*)l1 + da;
            const uint Dm1 = pa[-1], D0 = pa[0], D1 = pa[1], D2 = pa[2], D3 = pa[3];

            union { uint w[4]; bf16x8 v; int4 i4; } f1, f0, g0, g1u;
            f1.w[0] = D0; f1.w[1] = D1; f1.w[2] = D2; f1.w[3] = D3;   // par=1
            f0.w[0] = (Dm1 >> 16) | (D0 << 16);                       // par=0
            f0.w[1] = (D0  >> 16) | (D1 << 16);
            f0.w[2] = (D1  >> 16) | (D2 << 16);
            f0.w[3] = (D2  >> 16) | (D3 << 16);

            g0.i4  = evenU ? pkE : pkO;      // tile0 (step S), from global pipe
            g1u.i4 = fifo[u];                // tile1 (= tile0 @ S-16)
            fifo[u] = g0.i4;

            a00 = __builtin_amdgcn_mfma_f32_16x16x32_bf16(f0.v, g0.v,  a00, 0, 0, 0);
            a10 = __builtin_amdgcn_mfma_f32_16x16x32_bf16(f1.v, g0.v,  a10, 0, 0, 0);
            a01 = __builtin_amdgcn_mfma_f32_16x16x32_bf16(f0.v, g1u.v, a01, 0, 0, 0);
            a11 = __builtin_amdgcn_mfma_f32_16x16x32_bf16(f1.v, g1u.v, a11, 0, 0, 0);

            // Pack the held f32 pair -> frag for step S+1.
            {
                if (evenU) { const int4 pv = packB(fBx, fBy); pkO = okB_ ? pv : int4{0,0,0,0}; }
                else       { const int4 pv = packB(fAx, fAy); pkE = okA_ ? pv : int4{0,0,0,0}; }
            }

            da += 16;
        }

        // A convert + LDS write (read by later chunks).
        if (okSt) {
            int4 p;
            p.x = pk2(va0.x, va0.y);
            p.y = pk2(va0.z, va0.w);
            p.z = pk2(va1.x, va1.y);
            p.w = pk2(va1.z, va1.w);
            *(int4*)(l1 + dA) = p;
        }
        aPre += 256;
    }

    // --- Store: lane (q,r), reg rr, parity p -> o = 512*tile + 32r + 8q + 2rr + p.
    float* o = out + (size_t)ch * NOUT;
    {
        const int X = 32 * r + 8 * q;            // tile0: X+7 <= 511 < 603
        float4 s0 = {a00[0], a10[0], a00[1], a10[1]};
        float4 s1 = {a00[2], a10[2], a00[3], a10[3]};
        *(float4*)(o + X)     = s0;
        *(float4*)(o + X + 4) = s1;
    }
    {
        const int X = 512 + 32 * r + 8 * q;
        if (X + 7 < NOUT) {
            float4 s0 = {a01[0], a11[0], a01[1], a11[1]};
            float4 s1 = {a01[2], a11[2], a01[3], a11[3]};
            *(float4*)(o + X)     = s0;
            *(float4*)(o + X + 4) = s1;
        } else if (X < NOUT) {
            const float v[8] = {a01[0], a11[0], a01[1], a11[1],
                                a01[2], a11[2], a01[3], a11[3]};
            #pragma unroll
            for (int e = 0; e < 8; ++e)
                if (X + e < NOUT) o[X + e] = v[e];
        }
    }
}

extern "C" void kernel_launch(void* const* d_in, const int* in_sizes, int n_in,
                              void* d_out, int out_size, void* d_ws, size_t ws_size,
                              hipStream_t stream) {
    const float* d1 = (const float*)d_in[0];
    const float* d2 = (const float*)d_in[1];
    float* out = (float*)d_out;
    const int nChannels = in_sizes[0] / NT;     // 2048
    xcorr_mfma<<<nChannels, BLOCK, 0, stream>>>(d1, d2, out);
}